// Round 10
// baseline (233.283 us; speedup 1.0000x reference)
//
#include <hip/hip_runtime.h>

// MultiHeadAttention with memory tokens + residual + LayerNorm.
// Inputs f32 (mask int32), OUTPUT f32.  B=4, N=1024, D=1024, H=16, DK=64,
// M=64, NKV=1088.  Intermediates bf16 (MFMA), f32 accumulation.
//
// R19: gemm K-length back to COMPILE-TIME (template<int KLEN>) — R18's
// runtime g.klen loop bound cost QKV ~20% (44.5->53us, codegen).  K-split
// O-proj kept: two <512> slices (z=0/1), f32 partials to dead workspace,
// residual_ln2 sums x+y0+y1.  k0 stays runtime (loop-invariant add).
// R16: attn dbuf 1-barrier/iter, permlane32_swap P-exchange, defer-max.
// R15: 32x32x16 MFMA attn, swapped QK^T, in-reg softmax, O^T PV.
// R13: XCD head-group swizzle.  R10: bf16 prep + glds gemm.

typedef __bf16 bf16;
typedef __bf16 bf16x8 __attribute__((ext_vector_type(8)));
typedef __bf16 bf16x4 __attribute__((ext_vector_type(4)));
typedef __bf16 bf16x2 __attribute__((ext_vector_type(2)));
typedef float  f32x4  __attribute__((ext_vector_type(4)));
typedef float  f32x16 __attribute__((ext_vector_type(16)));
typedef unsigned uintx4 __attribute__((ext_vector_type(4)));

#define NSEQ 1024
#define NKV  1088
#define DMODEL 1024

struct CvtArgs { const float* s[7]; const float* mk; const float* mv; };

// ---------------------------------------------------------------------------
// prep: f32->bf16 conversion of all GEMM operands into one contiguous dst
// ([q 4Mi][k 4Mi][v 4Mi][Wq 1Mi][Wk 1Mi][Wv 1Mi][Wo 1Mi]) + memory-token
// fill of Kb rows 1024..1087 and Vt cols 1024..1087 (blocks >= 8192).
__global__ __launch_bounds__(256) void prep(CvtArgs c, bf16* __restrict__ dst,
                                            bf16* __restrict__ Kb,
                                            bf16* __restrict__ Vt)
{
    int blk = blockIdx.x;
    if (blk < 8192) {
        size_t e = ((size_t)blk * 256 + threadIdx.x) * 8;
        const float* s;
        if (e < ((size_t)3 << 22)) {
            s = c.s[e >> 22] + (e & 0x3FFFFF);
        } else {
            size_t wq = e - ((size_t)3 << 22);
            s = c.s[3 + (wq >> 20)] + (wq & 0xFFFFF);
        }
        f32x4 a = *(const f32x4*)s;
        f32x4 b = *(const f32x4*)(s + 4);
        bf16x8 o;
        for (int i = 0; i < 4; i++) { o[i] = (bf16)a[i]; o[4 + i] = (bf16)b[i]; }
        *(bf16x8*)&dst[e] = o;
    } else {
        int i = (blk - 8192) * 256 + threadIdx.x;   // [0, 262144)
        int b = i >> 16, md = i & 65535;
        int m = md >> 10, dcol = md & 1023;
        Kb[(size_t)b * (NKV * DMODEL) + (size_t)(NSEQ + m) * DMODEL + dcol]
            = (bf16)(c.mk[md] * 8.0f);
        Vt[((size_t)b * 1024 + dcol) * NKV + NSEQ + m] = (bf16)(c.mv[md] * 8.0f);
    }
}

// ---------------------------------------------------------------------------
// async global->LDS, 16 B per lane (wave-uniform LDS base + lane*16 in HW)
typedef __attribute__((address_space(1))) void gas_void;
typedef __attribute__((address_space(3))) void las_void;

__device__ __forceinline__ void gload16(const bf16* g, bf16* l)
{
    __builtin_amdgcn_global_load_lds((gas_void*)g, (las_void*)l, 16, 0, 0);
}

struct GemmArgsB {
    const bf16* A;        // [M][1024] bf16
    const bf16* W;        // [1024][1024] bf16
    const float* bias;    // [1024] f32 (nullptr = 0)
    void* C;              // bf16 (vt 0/1) or f32 (vt 2)
    int osK;              // batch stride for multi-batch row remap (vt=0)
    int vt;               // 0: bf16 row-major, 1: V-transposed, 2: f32 flat
    int k0;               // K-slice start (runtime, loop-invariant)
};

// C = A @ W.T + bias.  128x128 tile, BK=32, 4 waves (2x2), 4x4 16x16 frags.
// Staging: global_load_lds dwordx4 into linear LDS [128][32] (m97 structure).
// KLEN is compile-time: the K-loop trip count must be static for the
// compiler's cross-iteration scheduling (R18 lesson: runtime bound = -20%).
template<int KLEN>
__device__ __forceinline__ void gemm128_body(const GemmArgsB g, int bx, int by)
{
    __shared__ bf16 As[128][32];
    __shared__ bf16 Bs[128][32];
    const int t = threadIdx.x;
    const int lane = t & 63, w = t >> 6;
    const int qi = lane & 15, qq = lane >> 4;
    const int wrow = (w >> 1) * 64, wcol = (w & 1) * 64;
    const int bm = by * 128, bn = bx * 128;

    // wave w stages rows [w*32, w*32+32) of A and B: two 1 KB DMAs each.
    const int srow = w * 32 + (lane >> 2);
    const int scol = (lane & 3) * 8;
    const bf16* Ag = g.A + (size_t)(bm + srow) * DMODEL + g.k0 + scol;
    const bf16* Wg = g.W + (size_t)(bn + srow) * DMODEL + g.k0 + scol;
    bf16* Al = &As[w * 32][0];
    bf16* Bl = &Bs[w * 32][0];

    f32x4 acc[4][4] = {};

#define STAGE(kt)                                                             \
    do {                                                                      \
        gload16(Ag + (kt),                 Al);                               \
        gload16(Ag + (kt) + 16 * DMODEL,   Al + 16 * 32);                     \
        gload16(Wg + (kt),                 Bl);                               \
        gload16(Wg + (kt) + 16 * DMODEL,   Bl + 16 * 32);                    \
    } while (0)

    STAGE(0);
    for (int kt = 0; kt < KLEN; kt += 32) {
        __syncthreads();                       // DMA for tile kt complete
        bf16x8 a[4], b[4];
        for (int i = 0; i < 4; i++)
            a[i] = *(const bf16x8*)&As[wrow + i * 16 + qi][qq * 8];
        for (int j = 0; j < 4; j++)
            b[j] = *(const bf16x8*)&Bs[wcol + j * 16 + qi][qq * 8];
        __syncthreads();                       // all waves done reading LDS
        if (kt + 32 < KLEN) STAGE(kt + 32);    // DMA overlaps MFMAs below
        for (int i = 0; i < 4; i++)
            for (int j = 0; j < 4; j++)
                acc[i][j] = __builtin_amdgcn_mfma_f32_16x16x32_bf16(
                    a[i], b[j], acc[i][j], 0, 0, 0);
    }
#undef STAGE

    // epilogue; C/D layout row=qq*4+r, col=qi  [m89-verified]
    for (int i = 0; i < 4; i++)
        for (int j = 0; j < 4; j++) {
            int row0 = bm + wrow + i * 16 + qq * 4;
            int col  = bn + wcol + j * 16 + qi;
            float bcol = g.bias ? g.bias[col] : 0.0f;
            if (g.vt == 1) {
                bf16x4 v;
                for (int r = 0; r < 4; r++) v[r] = (bf16)(acc[i][j][r] + bcol);
                size_t off = ((size_t)((row0 >> 10) * 16 + (col >> 6)) * 64 + (col & 63))
                           * NKV + (row0 & 1023);
                *(bf16x4*)&((bf16*)g.C)[off] = v;
            } else if (g.vt == 2) {
                float* Cf = (float*)g.C;
                for (int r = 0; r < 4; r++) {
                    int row = row0 + r;
                    Cf[(size_t)row * DMODEL + col] = acc[i][j][r] + bcol;
                }
            } else {
                bf16* Cb = (bf16*)g.C;
                for (int r = 0; r < 4; r++) {
                    int row = row0 + r;
                    size_t off = (size_t)(row >> 10) * g.osK
                               + (size_t)(row & 1023) * DMODEL + col;
                    Cb[off] = (bf16)(acc[i][j][r] + bcol);
                }
            }
        }
}

template<int KLEN>
__global__ __launch_bounds__(256, 3) void gemm128_lds(GemmArgsB g0, GemmArgsB g1,
                                                      GemmArgsB g2)
{
    const GemmArgsB g = (blockIdx.z == 0) ? g0 : (blockIdx.z == 1) ? g1 : g2;
    gemm128_body<KLEN>(g, blockIdx.x, blockIdx.y);
}

// ---------------------------------------------------------------------------
// Old f32-staged GEMM — kept for small-workspace fallback paths.
struct GemmArgs {
    const void* A;
    const float* W;
    const float* bias;
    bf16* C;
    int osK;
    int vt;
};

template<bool ABF>
__global__ __launch_bounds__(256, 2) void gemm128(GemmArgs g0, GemmArgs g1, GemmArgs g2)
{
    const GemmArgs g = (blockIdx.z == 0) ? g0 : (blockIdx.z == 1) ? g1 : g2;
    __shared__ bf16 As[128][44];
    __shared__ bf16 Bs[128][44];
    const int t = threadIdx.x;
    const int lane = t & 63, w = t >> 6;
    const int qi = lane & 15, qq = lane >> 4;
    const int wrow = (w >> 1) * 64, wcol = (w & 1) * 64;
    const int bm = blockIdx.y * 128, bn = blockIdx.x * 128;
    const int sr = t >> 1, sc = (t & 1) * 16;

    f32x4 acc[4][4] = {};

    f32x4 pa[4];
    bf16x8 pab[2];
    f32x4 pw[4];

    const float* Wp = g.W + (size_t)(bn + sr) * DMODEL + sc;
    const float* Af = (const float*)g.A + (size_t)(bm + sr) * DMODEL + sc;
    const bf16*  Ab = (const bf16*)g.A + (size_t)(bm + sr) * DMODEL + sc;

#define LOAD_TILES(kt)                                                        \
    do {                                                                      \
        if (ABF) {                                                            \
            pab[0] = *(const bf16x8*)(Ab + (kt));                             \
            pab[1] = *(const bf16x8*)(Ab + (kt) + 8);                         \
        } else {                                                              \
            pa[0] = *(const f32x4*)(Af + (kt));                               \
            pa[1] = *(const f32x4*)(Af + (kt) + 4);                           \
            pa[2] = *(const f32x4*)(Af + (kt) + 8);                           \
            pa[3] = *(const f32x4*)(Af + (kt) + 12);                          \
        }                                                                     \
        pw[0] = *(const f32x4*)(Wp + (kt));                                   \
        pw[1] = *(const f32x4*)(Wp + (kt) + 4);                               \
        pw[2] = *(const f32x4*)(Wp + (kt) + 8);                               \
        pw[3] = *(const f32x4*)(Wp + (kt) + 12);                              \
    } while (0)

#define STORE_TILES()                                                         \
    do {                                                                      \
        if (ABF) {                                                            \
            *(bf16x8*)&As[sr][sc]     = pab[0];                               \
            *(bf16x8*)&As[sr][sc + 8] = pab[1];                               \
        } else {                                                              \
            bf16x8 v0, v1;                                                    \
            for (int i = 0; i < 4; i++) {                                     \
                v0[i] = (bf16)pa[0][i]; v0[4 + i] = (bf16)pa[1][i];           \
                v1[i] = (bf16)pa[2][i]; v1[4 + i] = (bf16)pa[3][i];           \
            }                                                                 \
            *(bf16x8*)&As[sr][sc]     = v0;                                   \
            *(bf16x8*)&As[sr][sc + 8] = v1;                                   \
        }                                                                     \
        {                                                                     \
            bf16x8 u0, u1;                                                    \
            for (int i = 0; i < 4; i++) {                                     \
                u0[i] = (bf16)pw[0][i]; u0[4 + i] = (bf16)pw[1][i];           \
                u1[i] = (bf16)pw[2][i]; u1[4 + i] = (bf16)pw[3][i];           \
            }                                                                 \
            *(bf16x8*)&Bs[sr][sc]     = u0;                                   \
            *(bf16x8*)&Bs[sr][sc + 8] = u1;                                   \
        }                                                                     \
    } while (0)

    LOAD_TILES(0);
    STORE_TILES();
    __syncthreads();

    for (int kt = 0; kt < DMODEL; kt += 32) {
        const bool more = (kt + 32) < DMODEL;
        if (more) LOAD_TILES(kt + 32);
        bf16x8 a[4], b[4];
        for (int i = 0; i < 4; i++)
            a[i] = *(const bf16x8*)&As[wrow + i * 16 + qi][qq * 8];
        for (int j = 0; j < 4; j++)
            b[j] = *(const bf16x8*)&Bs[wcol + j * 16 + qi][qq * 8];
        for (int i = 0; i < 4; i++)
            for (int j = 0; j < 4; j++)
                acc[i][j] = __builtin_amdgcn_mfma_f32_16x16x32_bf16(a[i], b[j], acc[i][j], 0, 0, 0);
        if (more) {
            __syncthreads();
            STORE_TILES();
            __syncthreads();
        }
    }
#undef LOAD_TILES
#undef STORE_TILES

    for (int i = 0; i < 4; i++)
        for (int j = 0; j < 4; j++) {
            int row0 = bm + wrow + i * 16 + qq * 4;
            int col  = bn + wcol + j * 16 + qi;
            float bcol = g.bias[col];
            if (g.vt) {
                bf16x4 v;
                for (int r = 0; r < 4; r++) v[r] = (bf16)(acc[i][j][r] + bcol);
                size_t off = ((size_t)((row0 >> 10) * 16 + (col >> 6)) * 64 + (col & 63))
                           * NKV + (row0 & 1023);
                *(bf16x4*)&g.C[off] = v;
            } else {
                for (int r = 0; r < 4; r++) {
                    int row = row0 + r;
                    size_t off = (size_t)(row >> 10) * g.osK
                               + (size_t)(row & 1023) * DMODEL + col;
                    g.C[off] = (bf16)(acc[i][j][r] + bcol);
                }
            }
        }
}

// ---------------------------------------------------------------------------
// standalone memory-token fill (fallback paths only)
__global__ void fill_mem(const float* __restrict__ mk, const float* __restrict__ mv,
                         bf16* __restrict__ K, bf16* __restrict__ Vt)
{
    int i = blockIdx.x * 256 + threadIdx.x;
    int b = i >> 16, md = i & 65535;
    int m = md >> 10, dcol = md & 1023;
    K[(size_t)b * (NKV * DMODEL) + (size_t)(NSEQ + m) * DMODEL + dcol]
        = (bf16)(mk[md] * 8.0f);
    Vt[((size_t)b * 1024 + dcol) * NKV + NSEQ + m] = (bf16)(mv[md] * 8.0f);
}

// ---------------------------------------------------------------------------
__device__ __forceinline__ unsigned pkbf(float a, float b)
{
    bf16x2 t; t[0] = (bf16)a; t[1] = (bf16)b;
    unsigned u; __builtin_memcpy(&u, &t, 4); return u;
}

// Flash attention v5: 32x32x16 MFMA, 32 q-rows/wave, 128 q-rows/block.
// grid (NSEQ/128, nb*16).  Swapped QK^T: lane l holds S^T[k][q=l&31].
// sKV double-buffered -> 1 barrier/iter.  P-frag exchange via
// v_permlane32_swap.  Defer-max (thr=8) skips alpha/rescale on most tiles.
__global__ __launch_bounds__(256) void attn_flash(const bf16* Q,
        const bf16* __restrict__ K, const bf16* __restrict__ Vt,
        const int* __restrict__ mask, bf16* O)
{
    __shared__ bf16 sKV[2][2][64][72];         // [buf][K,V][row][col]
    __shared__ __align__(16) float sM[NKV];
    const int t = threadIdx.x, lane = t & 63, w = t >> 6;
    int bh, q0;
    if (gridDim.y == 64) {
        // head-grouping swizzle: 8 (b,h) pairs + all their q-blocks per XCD
        int lin = blockIdx.y * gridDim.x + blockIdx.x;
        bh = ((lin & 7) << 3) | ((lin >> 3) & 7);
        q0 = (lin >> 6) * 128;
    } else {
        bh = blockIdx.y;
        q0 = blockIdx.x * 128;
    }
    const int b = bh >> 4, h = bh & 15;
    const int sr = t >> 2, sc = (t & 3) * 16;  // K/V staging map
    const int lq = lane & 31, hi = lane >> 5;

    for (int j = t; j < NKV; j += 256)
        sM[j] = (j < NSEQ && mask[b * NSEQ + j] != 0) ? -3.0e38f : 0.0f;

    // Q B-frags (n = q = lq, c-chunk c': d = c'*16 + hi*8 + j), scaled 1/8
    const size_t qrow = (size_t)(b * NSEQ + q0 + w * 32 + lq) * DMODEL + h * 64;
    bf16x8 qf[4];
#pragma unroll
    for (int c = 0; c < 4; c++) {
        bf16x8 v = *(const bf16x8*)&Q[qrow + c * 16 + hi * 8];
        for (int i = 0; i < 8; i++) v[i] = (bf16)((float)v[i] * 0.125f);
        qf[c] = v;
    }

    const bf16* kbase = K + (size_t)(b * NKV + sr) * DMODEL + h * 64 + sc;
    const bf16* vbase = Vt + ((size_t)bh * 64 + sr) * NKV + sc;

    bf16x8 pk0, pk1, pv0, pv1;
#define LOAD_KV(jt)                                                           \
    do {                                                                      \
        const bf16* kp = kbase + (size_t)(jt) * 64 * DMODEL;                  \
        pk0 = *(const bf16x8*)kp;                                             \
        pk1 = *(const bf16x8*)(kp + 8);                                       \
        const bf16* vp = vbase + (jt) * 64;                                   \
        pv0 = *(const bf16x8*)vp;                                             \
        pv1 = *(const bf16x8*)(vp + 8);                                       \
    } while (0)
#define STORE_KV(bi)                                                          \
    do {                                                                      \
        *(bf16x8*)&sKV[bi][0][sr][sc]     = pk0;                              \
        *(bf16x8*)&sKV[bi][0][sr][sc + 8] = pk1;                              \
        *(bf16x8*)&sKV[bi][1][sr][sc]     = pv0;                              \
        *(bf16x8*)&sKV[bi][1][sr][sc + 8] = pv1;                              \
    } while (0)

    LOAD_KV(0);
    STORE_KV(0);

    float m_i = -1.0e30f, l_i = 0.f;           // per-lane, q = lq
    f32x16 oacc0 = {}, oacc1 = {};             // O^T, dblk 0/1

    for (int jt = 0; jt < 17; jt++) {
        const int j0 = jt * 64;
        const int cb = jt & 1;
        const bool more = jt < 16;
        if (more) LOAD_KV(jt + 1);             // reg prefetch (global)
        __syncthreads();                       // buf[cb] staged & prior reads done

        // swapped QK^T (mask as C-init): accs[kb] = S^T[kb*32 + kl][q=lq],
        // kl = (r&3)+8*(r>>2)+4*hi
        f32x16 accs[2];
#pragma unroll
        for (int kb = 0; kb < 2; kb++) {
#pragma unroll
            for (int g2 = 0; g2 < 4; g2++) {
                f32x4 m4 = *(const f32x4*)&sM[j0 + kb * 32 + 8 * g2 + 4 * hi];
                accs[kb][4 * g2 + 0] = m4[0];
                accs[kb][4 * g2 + 1] = m4[1];
                accs[kb][4 * g2 + 2] = m4[2];
                accs[kb][4 * g2 + 3] = m4[3];
            }
#pragma unroll
            for (int c = 0; c < 4; c++) {
                bf16x8 kf = *(const bf16x8*)&sKV[cb][0][kb * 32 + lq][c * 16 + hi * 8];
                accs[kb] = __builtin_amdgcn_mfma_f32_32x32x16_bf16(
                    kf, qf[c], accs[kb], 0, 0, 0);
            }
        }

        // in-register softmax (pair l, l^32 holds all 64 k); 2-chain ILP
        float rm0 = accs[0][0], rm1 = accs[1][0];
#pragma unroll
        for (int r = 1; r < 16; r++) {
            rm0 = fmaxf(rm0, accs[0][r]);
            rm1 = fmaxf(rm1, accs[1][r]);
        }
        float rm = fmaxf(rm0, rm1);
        rm = fmaxf(rm, __shfl_xor(rm, 32, 64));
        // defer-max: only rescale when max grew by > 8 (T13)
        if (!__all(rm - m_i <= 8.0f)) {
            float mnew = fmaxf(m_i, rm);
            float alpha = __expf(m_i - mnew);
            m_i = mnew;
            l_i *= alpha;
#pragma unroll
            for (int r = 0; r < 16; r++) { oacc0[r] *= alpha; oacc1[r] *= alpha; }
        }
        float rs0 = 0.f, rs1 = 0.f;
#pragma unroll
        for (int r = 0; r < 16; r++) {
            float p0 = __expf(accs[0][r] - m_i);
            float p1 = __expf(accs[1][r] - m_i);
            accs[0][r] = p0; accs[1][r] = p1;
            rs0 += p0; rs1 += p1;
        }
        float rs = rs0 + rs1;
        rs += __shfl_xor(rs, 32, 64);
        l_i += rs;

        // pack P to bf16 dwords; dwv[kb*8+2a+d] = P[kl=8a+4hi+2d+{0,1}]
        unsigned dwv[16];
#pragma unroll
        for (int kb = 0; kb < 2; kb++)
#pragma unroll
            for (int a = 0; a < 4; a++) {
                dwv[kb * 8 + 2 * a]     = pkbf(accs[kb][4 * a], accs[kb][4 * a + 1]);
                dwv[kb * 8 + 2 * a + 1] = pkbf(accs[kb][4 * a + 2], accs[kb][4 * a + 3]);
            }
        // half-exchange lane<->lane^32 -> pb[c]: P[q=lq][k=c*16+hi*8+j]
        bf16x8 pb[4];
#pragma unroll
        for (int c = 0; c < 4; c++) {
            const int base = (c >> 1) * 8 + (c & 1) * 4;
            unsigned e0 = dwv[base],     e1 = dwv[base + 1];
            unsigned o0 = dwv[base + 2], o1 = dwv[base + 3];
            uintx4 cw;
#if __has_builtin(__builtin_amdgcn_permlane32_swap)
            auto r0 = __builtin_amdgcn_permlane32_swap(e0, o0, false, false);
            auto r1 = __builtin_amdgcn_permlane32_swap(e1, o1, false, false);
            cw[0] = r0[0]; cw[1] = r1[0]; cw[2] = r0[1]; cw[3] = r1[1];
#else
            unsigned s0 = hi ? e0 : o0, s1 = hi ? e1 : o1;
            unsigned k0 = hi ? o0 : e0, k1 = hi ? o1 : e1;
            unsigned x0 = __shfl_xor((int)s0, 32, 64);
            unsigned x1 = __shfl_xor((int)s1, 32, 64);
            cw[0] = hi ? x0 : k0; cw[1] = hi ? x1 : k1;
            cw[2] = hi ? k0 : x0; cw[3] = hi ? k1 : x1;
#endif
            __builtin_memcpy(&pb[c], &cw, 16);
        }

        // PV: O^T[d][q] += V^T[d][k] P[q][k]
#pragma unroll
        for (int c = 0; c < 4; c++) {
            bf16x8 vf0 = *(const bf16x8*)&sKV[cb][1][lq][c * 16 + hi * 8];
            bf16x8 vf1 = *(const bf16x8*)&sKV[cb][1][32 + lq][c * 16 + hi * 8];
            oacc0 = __builtin_amdgcn_mfma_f32_32x32x16_bf16(vf0, pb[c], oacc0, 0, 0, 0);
            oacc1 = __builtin_amdgcn_mfma_f32_32x32x16_bf16(vf1, pb[c], oacc1, 0, 0, 0);
        }
        if (more) STORE_KV(cb ^ 1);            // other buffer; safe post-barrier
    }
#undef LOAD_KV
#undef STORE_KV

    // transpose O^T -> O via LDS bounce (sKV dead after barrier)
    float linv = 1.0f / l_i;
    __syncthreads();
    bf16 (*sO)[72] = reinterpret_cast<bf16(*)[72]>(&sKV[0][0][0][0]);
#pragma unroll
    for (int r = 0; r < 16; r++) {
        int dl = (r & 3) + 8 * (r >> 2) + 4 * hi;
        sO[w * 32 + lq][dl]      = (bf16)(oacc0[r] * linv);
        sO[w * 32 + lq][32 + dl] = (bf16)(oacc1[r] * linv);
    }
    __syncthreads();
    {
        int row = t >> 1, ch = (t & 1) * 32;
        bf16* dst = &O[(size_t)(b * NSEQ + q0 + row) * DMODEL + h * 64 + ch];
#pragma unroll
        for (int k = 0; k < 4; k++)
            *(bf16x8*)(dst + k * 8) = *(const bf16x8*)&sO[row][ch + k * 8];
    }
}

// ---------------------------------------------------------------------------
// residual + LN over two f32 partial-product arrays (main path)
__global__ __launch_bounds__(256) void residual_ln2(const float* __restrict__ X,
        const float* __restrict__ Y0, const float* __restrict__ Y1,
        const float* __restrict__ gamma, const float* __restrict__ beta,
        float* __restrict__ out)
{
    __shared__ float red[8];
    int row = blockIdx.x, t = threadIdx.x;
    size_t base = (size_t)row * DMODEL + t * 4;
    f32x4 xv = *(const f32x4*)&X[base];
    f32x4 y0 = *(const f32x4*)&Y0[base];
    f32x4 y1 = *(const f32x4*)&Y1[base];
    float s[4], sum = 0.f, sq = 0.f;
    for (int i = 0; i < 4; i++) {
        s[i] = xv[i] + y0[i] + y1[i];
        sum += s[i]; sq += s[i] * s[i];
    }
    for (int o = 32; o; o >>= 1) { sum += __shfl_xor(sum, o, 64); sq += __shfl_xor(sq, o, 64); }
    if ((t & 63) == 0) { red[t >> 6] = sum; red[4 + (t >> 6)] = sq; }
    __syncthreads();
    sum = red[0] + red[1] + red[2] + red[3];
    sq  = red[4] + red[5] + red[6] + red[7];
    float mean = sum * (1.0f / DMODEL);
    float var  = sq  * (1.0f / DMODEL) - mean * mean;
    float rstd = rsqrtf(var + 1e-5f);
    f32x4 gv = *(const f32x4*)&gamma[t * 4];
    f32x4 bv = *(const f32x4*)&beta[t * 4];
    f32x4 ov;
    for (int i = 0; i < 4; i++)
        ov[i] = (s[i] - mean) * rstd * gv[i] + bv[i];
    *(f32x4*)&out[base] = ov;
}

// bf16-partial variant (fallback paths)
__global__ __launch_bounds__(256) void residual_ln(const float* __restrict__ X,
        const bf16* __restrict__ Y, const float* __restrict__ gamma,
        const float* __restrict__ beta, float* __restrict__ out)
{
    __shared__ float red[8];
    int row = blockIdx.x, t = threadIdx.x;
    size_t base = (size_t)row * DMODEL + t * 4;
    f32x4  xv = *(const f32x4*)&X[base];
    bf16x4 yv = *(const bf16x4*)&Y[base];
    float s[4], sum = 0.f, sq = 0.f;
    for (int i = 0; i < 4; i++) {
        s[i] = xv[i] + (float)yv[i];
        sum += s[i]; sq += s[i] * s[i];
    }
    for (int o = 32; o; o >>= 1) { sum += __shfl_xor(sum, o, 64); sq += __shfl_xor(sq, o, 64); }
    if ((t & 63) == 0) { red[t >> 6] = sum; red[4 + (t >> 6)] = sq; }
    __syncthreads();
    sum = red[0] + red[1] + red[2] + red[3];
    sq  = red[4] + red[5] + red[6] + red[7];
    float mean = sum * (1.0f / DMODEL);
    float var  = sq  * (1.0f / DMODEL) - mean * mean;
    float rstd = rsqrtf(var + 1e-5f);
    f32x4 gv = *(const f32x4*)&gamma[t * 4];
    f32x4 bv = *(const f32x4*)&beta[t * 4];
    f32x4 ov;
    for (int i = 0; i < 4; i++)
        ov[i] = (s[i] - mean) * rstd * gv[i] + bv[i];
    *(f32x4*)&out[base] = ov;
}

// ---------------------------------------------------------------------------
extern "C" void kernel_launch(void* const* d_in, const int* in_sizes, int n_in,
                              void* d_out, int out_size, void* d_ws, size_t ws_size,
                              hipStream_t stream)
{
    const float* queries = (const float*)d_in[0];
    const float* keys    = (const float*)d_in[1];
    const float* values  = (const float*)d_in[2];
    const int*   amask   = (const int*)d_in[3];
    const float* Wq = (const float*)d_in[4];  const float* bq = (const float*)d_in[5];
    const float* Wk = (const float*)d_in[6];  const float* bk = (const float*)d_in[7];
    const float* Wv = (const float*)d_in[8];  const float* bv = (const float*)d_in[9];
    const float* Wo = (const float*)d_in[10]; const float* bo = (const float*)d_in[11];
    const float* mk = (const float*)d_in[12]; const float* mv = (const float*)d_in[13];
    const float* gamma = (const float*)d_in[14]; const float* beta = (const float*)d_in[15];
    float* out = (float*)d_out;

    bf16* Qb = (bf16*)(out + (size_t)2 * 1024 * 1024);   // d_out upper 8 MB
    const size_t SB  = (size_t)NSEQ * DMODEL;            // 1,048,576 elems
    const size_t KVB = (size_t)NKV * DMODEL;             // 1,114,112 elems
    dim3 gb(256);

    // main path needs Kb + Vt + Ab(q,k,v bf16) + Wb(4 matrices bf16):
    const size_t need_r10 = (2 * 4 * KVB + 3 * 4 * SB + 4 * SB) * sizeof(bf16);

    if (ws_size >= need_r10) {
        // ---------- bf16 + global_load_lds path (ws >= ~49 MB) ----------
        bf16* Kb = (bf16*)d_ws;            // [4][1088][1024]
        bf16* Vt = Kb + 4 * KVB;           // [4*16*64][1088]
        bf16* Ab = Vt + 4 * KVB;           // [3][4][1024][1024] bf16 (q,k,v)
        bf16* Wb = Ab + 12 * SB;           // [4][1024][1024] bf16 (Wq,Wk,Wv,Wo)
        // f32 partial-product buffers for the K-split O-proj (dead regions):
        float* PR0 = (float*)Ab;           // 16 MB in dead Ab (24 MB)
        float* PR1 = (float*)d_ws;         // 16 MB in dead Kb+Vt (17.8 MB)

        CvtArgs ca;
        ca.s[0] = queries; ca.s[1] = keys; ca.s[2] = values;
        ca.s[3] = Wq; ca.s[4] = Wk; ca.s[5] = Wv; ca.s[6] = Wo;
        ca.mk = mk; ca.mv = mv;
        prep<<<dim3(8192 + 1024), gb, 0, stream>>>(ca, Ab, Kb, Vt);

        GemmArgsB gq{Ab,          Wb,          bq, Qb, (int)SB,  0, 0};
        GemmArgsB gk{Ab + 4 * SB, Wb + SB,     bk, Kb, (int)KVB, 0, 0};
        GemmArgsB gv{Ab + 8 * SB, Wb + 2 * SB, bv, Vt, 0,        1, 0};
        gemm128_lds<DMODEL><<<dim3(8, 32, 3), gb, 0, stream>>>(gq, gk, gv);

        attn_flash<<<dim3(8, 64), gb, 0, stream>>>(Qb, Kb, Vt, amask, Qb);

        // O-proj, 2-way K-split (z = slice), f32 partials; bias in slice 0
        GemmArgsB go0{Qb, Wb + 3 * SB, bo,      PR0, 0, 2, 0};
        GemmArgsB go1{Qb, Wb + 3 * SB, nullptr, PR1, 0, 2, 512};
        gemm128_lds<512><<<dim3(8, 32, 2), gb, 0, stream>>>(go0, go1, go1);

        residual_ln2<<<dim3(4096), gb, 0, stream>>>(queries, PR0, PR1,
                                                    gamma, beta, out);
    } else if (ws_size >= (size_t)2 * 4 * KVB * sizeof(bf16)) {
        // ---------- batched f32-staged fallback (ws >= 17,825,792 B) ----------
        bf16* Kb = (bf16*)d_ws;            // [4][1088][1024]
        bf16* Vt = Kb + 4 * KVB;           // [4*16*64][1088]
        bf16* PR = Kb;                     // [4096][1024] aliases dead Kb

        GemmArgs gq{queries, Wq, bq, Qb, (int)SB,  0};
        GemmArgs gk{keys,    Wk, bk, Kb, (int)KVB, 0};
        GemmArgs gv{values,  Wv, bv, Vt, 0,        1};
        gemm128<false><<<dim3(8, 32, 3), gb, 0, stream>>>(gq, gk, gv);
        fill_mem<<<dim3(1024), gb, 0, stream>>>(mk, mv, Kb, Vt);
        attn_flash<<<dim3(8, 64), gb, 0, stream>>>(Qb, Kb, Vt, amask, Qb);
        GemmArgs go{Qb, Wo, bo, PR, (int)SB, 0};
        gemm128<true><<<dim3(8, 32, 1), gb, 0, stream>>>(go, go, go);
        residual_ln<<<dim3(4096), gb, 0, stream>>>(queries, PR, gamma, beta, out);
    } else {
        // ---------- per-batch fallback (ws >= 4,456,448 B) ----------
        bf16* Kb = (bf16*)d_ws;            // [1088][1024]
        bf16* Vt = Kb + KVB;               // [16*64][1088]
        bf16* PR = Kb;

        GemmArgs gq{queries, Wq, bq, Qb, (int)SB, 0};
        gemm128<false><<<dim3(8, 32, 1), gb, 0, stream>>>(gq, gq, gq);
        for (int b = 0; b < 4; b++) {
            GemmArgs gk{keys   + b * SB, Wk, bk, Kb, 0, 0};
            GemmArgs gv{values + b * SB, Wv, bv, Vt, 0, 1};
            gemm128<false><<<dim3(8, 8, 2), gb, 0, stream>>>(gk, gv, gv);
            fill_mem<<<dim3(256), gb, 0, stream>>>(mk, mv, Kb, Vt);
            attn_flash<<<dim3(8, 16), gb, 0, stream>>>(Qb + b * SB, Kb, Vt,
                                                       amask + b * NSEQ, Qb + b * SB);
            GemmArgs go{Qb + b * SB, Wo, bo, PR, 0, 0};
            gemm128<true><<<dim3(8, 8, 1), gb, 0, stream>>>(go, go, go);
            residual_ln<<<dim3(1024), gb, 0, stream>>>(queries + b * SB, PR,
                                                       gamma, beta, out + b * SB);
        }
    }
}

// Round 11
// 227.387 us; speedup vs baseline: 1.0259x; 1.0259x over previous
//
#include <hip/hip_runtime.h>

// MultiHeadAttention with memory tokens + residual + LayerNorm.
// Inputs f32 (mask int32), OUTPUT f32.  B=4, N=1024, D=1024, H=16, DK=64,
// M=64, NKV=1088.  Intermediates bf16 (MFMA), f32 accumulation.
//
// R20: XCD data-partition swizzle for gemm128_lds — remap (x,y,z) so each
// XCD (lin%8) owns a DISJOINT 4-panel A-row slice and sweeps (x,z) within
// it (A 1MB + W 2MB < 4MB L2/XCD; no concurrent duplicate A misses).  Same
// mechanism as attn's R12 swizzle (FETCH 73.8->12.9 MB there).
// R19: template<int KLEN> compile-time K-loop (R18 runtime bound = -20%);
// O-proj 2-way K-split, f32 partials, residual_ln2.
// R16: attn dbuf 1-barrier/iter, permlane32_swap P-exchange, defer-max.
// R15: 32x32x16 MFMA attn, swapped QK^T, in-reg softmax, O^T PV.
// R13: XCD head-group swizzle.  R10: bf16 prep + glds gemm.

typedef __bf16 bf16;
typedef __bf16 bf16x8 __attribute__((ext_vector_type(8)));
typedef __bf16 bf16x4 __attribute__((ext_vector_type(4)));
typedef __bf16 bf16x2 __attribute__((ext_vector_type(2)));
typedef float  f32x4  __attribute__((ext_vector_type(4)));
typedef float  f32x16 __attribute__((ext_vector_type(16)));
typedef unsigned uintx4 __attribute__((ext_vector_type(4)));

#define NSEQ 1024
#define NKV  1088
#define DMODEL 1024

struct CvtArgs { const float* s[7]; const float* mk; const float* mv; };

// ---------------------------------------------------------------------------
// prep: f32->bf16 conversion of all GEMM operands into one contiguous dst
// ([q 4Mi][k 4Mi][v 4Mi][Wq 1Mi][Wk 1Mi][Wv 1Mi][Wo 1Mi]) + memory-token
// fill of Kb rows 1024..1087 and Vt cols 1024..1087 (blocks >= 8192).
__global__ __launch_bounds__(256) void prep(CvtArgs c, bf16* __restrict__ dst,
                                            bf16* __restrict__ Kb,
                                            bf16* __restrict__ Vt)
{
    int blk = blockIdx.x;
    if (blk < 8192) {
        size_t e = ((size_t)blk * 256 + threadIdx.x) * 8;
        const float* s;
        if (e < ((size_t)3 << 22)) {
            s = c.s[e >> 22] + (e & 0x3FFFFF);
        } else {
            size_t wq = e - ((size_t)3 << 22);
            s = c.s[3 + (wq >> 20)] + (wq & 0xFFFFF);
        }
        f32x4 a = *(const f32x4*)s;
        f32x4 b = *(const f32x4*)(s + 4);
        bf16x8 o;
        for (int i = 0; i < 4; i++) { o[i] = (bf16)a[i]; o[4 + i] = (bf16)b[i]; }
        *(bf16x8*)&dst[e] = o;
    } else {
        int i = (blk - 8192) * 256 + threadIdx.x;   // [0, 262144)
        int b = i >> 16, md = i & 65535;
        int m = md >> 10, dcol = md & 1023;
        Kb[(size_t)b * (NKV * DMODEL) + (size_t)(NSEQ + m) * DMODEL + dcol]
            = (bf16)(c.mk[md] * 8.0f);
        Vt[((size_t)b * 1024 + dcol) * NKV + NSEQ + m] = (bf16)(c.mv[md] * 8.0f);
    }
}

// ---------------------------------------------------------------------------
// async global->LDS, 16 B per lane (wave-uniform LDS base + lane*16 in HW)
typedef __attribute__((address_space(1))) void gas_void;
typedef __attribute__((address_space(3))) void las_void;

__device__ __forceinline__ void gload16(const bf16* g, bf16* l)
{
    __builtin_amdgcn_global_load_lds((gas_void*)g, (las_void*)l, 16, 0, 0);
}

struct GemmArgsB {
    const bf16* A;        // [M][1024] bf16
    const bf16* W;        // [1024][1024] bf16
    const float* bias;    // [1024] f32 (nullptr = 0)
    void* C;              // bf16 (vt 0/1) or f32 (vt 2)
    int osK;              // batch stride for multi-batch row remap (vt=0)
    int vt;               // 0: bf16 row-major, 1: V-transposed, 2: f32 flat
    int k0;               // K-slice start (runtime, loop-invariant)
};

// C = A @ W.T + bias.  128x128 tile, BK=32, 4 waves (2x2), 4x4 16x16 frags.
// Staging: global_load_lds dwordx4 into linear LDS [128][32] (m97 structure).
// KLEN is compile-time: the K-loop trip count must be static for the
// compiler's cross-iteration scheduling (R18 lesson: runtime bound = -20%).
template<int KLEN>
__device__ __forceinline__ void gemm128_body(const GemmArgsB g, int bx, int by)
{
    __shared__ bf16 As[128][32];
    __shared__ bf16 Bs[128][32];
    const int t = threadIdx.x;
    const int lane = t & 63, w = t >> 6;
    const int qi = lane & 15, qq = lane >> 4;
    const int wrow = (w >> 1) * 64, wcol = (w & 1) * 64;
    const int bm = by * 128, bn = bx * 128;

    // wave w stages rows [w*32, w*32+32) of A and B: two 1 KB DMAs each.
    const int srow = w * 32 + (lane >> 2);
    const int scol = (lane & 3) * 8;
    const bf16* Ag = g.A + (size_t)(bm + srow) * DMODEL + g.k0 + scol;
    const bf16* Wg = g.W + (size_t)(bn + srow) * DMODEL + g.k0 + scol;
    bf16* Al = &As[w * 32][0];
    bf16* Bl = &Bs[w * 32][0];

    f32x4 acc[4][4] = {};

#define STAGE(kt)                                                             \
    do {                                                                      \
        gload16(Ag + (kt),                 Al);                               \
        gload16(Ag + (kt) + 16 * DMODEL,   Al + 16 * 32);                     \
        gload16(Wg + (kt),                 Bl);                               \
        gload16(Wg + (kt) + 16 * DMODEL,   Bl + 16 * 32);                    \
    } while (0)

    STAGE(0);
    for (int kt = 0; kt < KLEN; kt += 32) {
        __syncthreads();                       // DMA for tile kt complete
        bf16x8 a[4], b[4];
        for (int i = 0; i < 4; i++)
            a[i] = *(const bf16x8*)&As[wrow + i * 16 + qi][qq * 8];
        for (int j = 0; j < 4; j++)
            b[j] = *(const bf16x8*)&Bs[wcol + j * 16 + qi][qq * 8];
        __syncthreads();                       // all waves done reading LDS
        if (kt + 32 < KLEN) STAGE(kt + 32);    // DMA overlaps MFMAs below
        for (int i = 0; i < 4; i++)
            for (int j = 0; j < 4; j++)
                acc[i][j] = __builtin_amdgcn_mfma_f32_16x16x32_bf16(
                    a[i], b[j], acc[i][j], 0, 0, 0);
    }
#undef STAGE

    // epilogue; C/D layout row=qq*4+r, col=qi  [m89-verified]
    for (int i = 0; i < 4; i++)
        for (int j = 0; j < 4; j++) {
            int row0 = bm + wrow + i * 16 + qq * 4;
            int col  = bn + wcol + j * 16 + qi;
            float bcol = g.bias ? g.bias[col] : 0.0f;
            if (g.vt == 1) {
                bf16x4 v;
                for (int r = 0; r < 4; r++) v[r] = (bf16)(acc[i][j][r] + bcol);
                size_t off = ((size_t)((row0 >> 10) * 16 + (col >> 6)) * 64 + (col & 63))
                           * NKV + (row0 & 1023);
                *(bf16x4*)&((bf16*)g.C)[off] = v;
            } else if (g.vt == 2) {
                float* Cf = (float*)g.C;
                for (int r = 0; r < 4; r++) {
                    int row = row0 + r;
                    Cf[(size_t)row * DMODEL + col] = acc[i][j][r] + bcol;
                }
            } else {
                bf16* Cb = (bf16*)g.C;
                for (int r = 0; r < 4; r++) {
                    int row = row0 + r;
                    size_t off = (size_t)(row >> 10) * g.osK
                               + (size_t)(row & 1023) * DMODEL + col;
                    Cb[off] = (bf16)(acc[i][j][r] + bcol);
                }
            }
        }
}

template<int KLEN>
__global__ __launch_bounds__(256, 3) void gemm128_lds(GemmArgsB g0, GemmArgsB g1,
                                                      GemmArgsB g2)
{
    int bx = blockIdx.x, by = blockIdx.y, bz = blockIdx.z;
    // R20 XCD swizzle: XCD = lin%8 owns a disjoint 4-panel A-row slice and
    // sweeps (x, z) within it.  Bijective for (8, 32, gz) grids.
    if (gridDim.x == 8 && gridDim.y == 32) {
        int lin = bx + 8 * (by + 32 * bz);
        int k = lin & 7, j = lin >> 3;
        bx = j & 7;
        by = k * 4 + ((j >> 3) & 3);
        bz = j >> 5;
    }
    const GemmArgsB g = (bz == 0) ? g0 : (bz == 1) ? g1 : g2;
    gemm128_body<KLEN>(g, bx, by);
}

// ---------------------------------------------------------------------------
// Old f32-staged GEMM — kept for small-workspace fallback paths.
struct GemmArgs {
    const void* A;
    const float* W;
    const float* bias;
    bf16* C;
    int osK;
    int vt;
};

template<bool ABF>
__global__ __launch_bounds__(256, 2) void gemm128(GemmArgs g0, GemmArgs g1, GemmArgs g2)
{
    const GemmArgs g = (blockIdx.z == 0) ? g0 : (blockIdx.z == 1) ? g1 : g2;
    __shared__ bf16 As[128][44];
    __shared__ bf16 Bs[128][44];
    const int t = threadIdx.x;
    const int lane = t & 63, w = t >> 6;
    const int qi = lane & 15, qq = lane >> 4;
    const int wrow = (w >> 1) * 64, wcol = (w & 1) * 64;
    const int bm = blockIdx.y * 128, bn = blockIdx.x * 128;
    const int sr = t >> 1, sc = (t & 1) * 16;

    f32x4 acc[4][4] = {};

    f32x4 pa[4];
    bf16x8 pab[2];
    f32x4 pw[4];

    const float* Wp = g.W + (size_t)(bn + sr) * DMODEL + sc;
    const float* Af = (const float*)g.A + (size_t)(bm + sr) * DMODEL + sc;
    const bf16*  Ab = (const bf16*)g.A + (size_t)(bm + sr) * DMODEL + sc;

#define LOAD_TILES(kt)                                                        \
    do {                                                                      \
        if (ABF) {                                                            \
            pab[0] = *(const bf16x8*)(Ab + (kt));                             \
            pab[1] = *(const bf16x8*)(Ab + (kt) + 8);                         \
        } else {                                                              \
            pa[0] = *(const f32x4*)(Af + (kt));                               \
            pa[1] = *(const f32x4*)(Af + (kt) + 4);                           \
            pa[2] = *(const f32x4*)(Af + (kt) + 8);                           \
            pa[3] = *(const f32x4*)(Af + (kt) + 12);                          \
        }                                                                     \
        pw[0] = *(const f32x4*)(Wp + (kt));                                   \
        pw[1] = *(const f32x4*)(Wp + (kt) + 4);                               \
        pw[2] = *(const f32x4*)(Wp + (kt) + 8);                               \
        pw[3] = *(const f32x4*)(Wp + (kt) + 12);                              \
    } while (0)

#define STORE_TILES()                                                         \
    do {                                                                      \
        if (ABF) {                                                            \
            *(bf16x8*)&As[sr][sc]     = pab[0];                               \
            *(bf16x8*)&As[sr][sc + 8] = pab[1];                               \
        } else {                                                              \
            bf16x8 v0, v1;                                                    \
            for (int i = 0; i < 4; i++) {                                     \
                v0[i] = (bf16)pa[0][i]; v0[4 + i] = (bf16)pa[1][i];           \
                v1[i] = (bf16)pa[2][i]; v1[4 + i] = (bf16)pa[3][i];           \
            }                                                                 \
            *(bf16x8*)&As[sr][sc]     = v0;                                   \
            *(bf16x8*)&As[sr][sc + 8] = v1;                                   \
        }                                                                     \
        {                                                                     \
            bf16x8 u0, u1;                                                    \
            for (int i = 0; i < 4; i++) {                                     \
                u0[i] = (bf16)pw[0][i]; u0[4 + i] = (bf16)pw[1][i];           \
                u1[i] = (bf16)pw[2][i]; u1[4 + i] = (bf16)pw[3][i];           \
            }                                                                 \
            *(bf16x8*)&Bs[sr][sc]     = u0;                                   \
            *(bf16x8*)&Bs[sr][sc + 8] = u1;                                   \
        }                                                                     \
    } while (0)

    LOAD_TILES(0);
    STORE_TILES();
    __syncthreads();

    for (int kt = 0; kt < DMODEL; kt += 32) {
        const bool more = (kt + 32) < DMODEL;
        if (more) LOAD_TILES(kt + 32);
        bf16x8 a[4], b[4];
        for (int i = 0; i < 4; i++)
            a[i] = *(const bf16x8*)&As[wrow + i * 16 + qi][qq * 8];
        for (int j = 0; j < 4; j++)
            b[j] = *(const bf16x8*)&Bs[wcol + j * 16 + qi][qq * 8];
        for (int i = 0; i < 4; i++)
            for (int j = 0; j < 4; j++)
                acc[i][j] = __builtin_amdgcn_mfma_f32_16x16x32_bf16(a[i], b[j], acc[i][j], 0, 0, 0);
        if (more) {
            __syncthreads();
            STORE_TILES();
            __syncthreads();
        }
    }
#undef LOAD_TILES
#undef STORE_TILES

    for (int i = 0; i < 4; i++)
        for (int j = 0; j < 4; j++) {
            int row0 = bm + wrow + i * 16 + qq * 4;
            int col  = bn + wcol + j * 16 + qi;
            float bcol = g.bias[col];
            if (g.vt) {
                bf16x4 v;
                for (int r = 0; r < 4; r++) v[r] = (bf16)(acc[i][j][r] + bcol);
                size_t off = ((size_t)((row0 >> 10) * 16 + (col >> 6)) * 64 + (col & 63))
                           * NKV + (row0 & 1023);
                *(bf16x4*)&g.C[off] = v;
            } else {
                for (int r = 0; r < 4; r++) {
                    int row = row0 + r;
                    size_t off = (size_t)(row >> 10) * g.osK
                               + (size_t)(row & 1023) * DMODEL + col;
                    g.C[off] = (bf16)(acc[i][j][r] + bcol);
                }
            }
        }
}

// ---------------------------------------------------------------------------
// standalone memory-token fill (fallback paths only)
__global__ void fill_mem(const float* __restrict__ mk, const float* __restrict__ mv,
                         bf16* __restrict__ K, bf16* __restrict__ Vt)
{
    int i = blockIdx.x * 256 + threadIdx.x;
    int b = i >> 16, md = i & 65535;
    int m = md >> 10, dcol = md & 1023;
    K[(size_t)b * (NKV * DMODEL) + (size_t)(NSEQ + m) * DMODEL + dcol]
        = (bf16)(mk[md] * 8.0f);
    Vt[((size_t)b * 1024 + dcol) * NKV + NSEQ + m] = (bf16)(mv[md] * 8.0f);
}

// ---------------------------------------------------------------------------
__device__ __forceinline__ unsigned pkbf(float a, float b)
{
    bf16x2 t; t[0] = (bf16)a; t[1] = (bf16)b;
    unsigned u; __builtin_memcpy(&u, &t, 4); return u;
}

// Flash attention v5: 32x32x16 MFMA, 32 q-rows/wave, 128 q-rows/block.
// grid (NSEQ/128, nb*16).  Swapped QK^T: lane l holds S^T[k][q=l&31].
// sKV double-buffered -> 1 barrier/iter.  P-frag exchange via
// v_permlane32_swap.  Defer-max (thr=8) skips alpha/rescale on most tiles.
__global__ __launch_bounds__(256) void attn_flash(const bf16* Q,
        const bf16* __restrict__ K, const bf16* __restrict__ Vt,
        const int* __restrict__ mask, bf16* O)
{
    __shared__ bf16 sKV[2][2][64][72];         // [buf][K,V][row][col]
    __shared__ __align__(16) float sM[NKV];
    const int t = threadIdx.x, lane = t & 63, w = t >> 6;
    int bh, q0;
    if (gridDim.y == 64) {
        // head-grouping swizzle: 8 (b,h) pairs + all their q-blocks per XCD
        int lin = blockIdx.y * gridDim.x + blockIdx.x;
        bh = ((lin & 7) << 3) | ((lin >> 3) & 7);
        q0 = (lin >> 6) * 128;
    } else {
        bh = blockIdx.y;
        q0 = blockIdx.x * 128;
    }
    const int b = bh >> 4, h = bh & 15;
    const int sr = t >> 2, sc = (t & 3) * 16;  // K/V staging map
    const int lq = lane & 31, hi = lane >> 5;

    for (int j = t; j < NKV; j += 256)
        sM[j] = (j < NSEQ && mask[b * NSEQ + j] != 0) ? -3.0e38f : 0.0f;

    // Q B-frags (n = q = lq, c-chunk c': d = c'*16 + hi*8 + j), scaled 1/8
    const size_t qrow = (size_t)(b * NSEQ + q0 + w * 32 + lq) * DMODEL + h * 64;
    bf16x8 qf[4];
#pragma unroll
    for (int c = 0; c < 4; c++) {
        bf16x8 v = *(const bf16x8*)&Q[qrow + c * 16 + hi * 8];
        for (int i = 0; i < 8; i++) v[i] = (bf16)((float)v[i] * 0.125f);
        qf[c] = v;
    }

    const bf16* kbase = K + (size_t)(b * NKV + sr) * DMODEL + h * 64 + sc;
    const bf16* vbase = Vt + ((size_t)bh * 64 + sr) * NKV + sc;

    bf16x8 pk0, pk1, pv0, pv1;
#define LOAD_KV(jt)                                                           \
    do {                                                                      \
        const bf16* kp = kbase + (size_t)(jt) * 64 * DMODEL;                  \
        pk0 = *(const bf16x8*)kp;                                             \
        pk1 = *(const bf16x8*)(kp + 8);                                       \
        const bf16* vp = vbase + (jt) * 64;                                   \
        pv0 = *(const bf16x8*)vp;                                             \
        pv1 = *(const bf16x8*)(vp + 8);                                       \
    } while (0)
#define STORE_KV(bi)                                                          \
    do {                                                                      \
        *(bf16x8*)&sKV[bi][0][sr][sc]     = pk0;                              \
        *(bf16x8*)&sKV[bi][0][sr][sc + 8] = pk1;                              \
        *(bf16x8*)&sKV[bi][1][sr][sc]     = pv0;                              \
        *(bf16x8*)&sKV[bi][1][sr][sc + 8] = pv1;                              \
    } while (0)

    LOAD_KV(0);
    STORE_KV(0);

    float m_i = -1.0e30f, l_i = 0.f;           // per-lane, q = lq
    f32x16 oacc0 = {}, oacc1 = {};             // O^T, dblk 0/1

    for (int jt = 0; jt < 17; jt++) {
        const int j0 = jt * 64;
        const int cb = jt & 1;
        const bool more = jt < 16;
        if (more) LOAD_KV(jt + 1);             // reg prefetch (global)
        __syncthreads();                       // buf[cb] staged & prior reads done

        // swapped QK^T (mask as C-init): accs[kb] = S^T[kb*32 + kl][q=lq],
        // kl = (r&3)+8*(r>>2)+4*hi
        f32x16 accs[2];
#pragma unroll
        for (int kb = 0; kb < 2; kb++) {
#pragma unroll
            for (int g2 = 0; g2 < 4; g2++) {
                f32x4 m4 = *(const f32x4*)&sM[j0 + kb * 32 + 8 * g2 + 4 * hi];
                accs[kb][4 * g2 + 0] = m4[0];
                accs[kb][4 * g2 + 1] = m4[1];
                accs[kb][4 * g2 + 2] = m4[2];
                accs[kb][4 * g2 + 3] = m4[3];
            }
#pragma unroll
            for (int c = 0; c < 4; c++) {
                bf16x8 kf = *(const bf16x8*)&sKV[cb][0][kb * 32 + lq][c * 16 + hi * 8];
                accs[kb] = __builtin_amdgcn_mfma_f32_32x32x16_bf16(
                    kf, qf[c], accs[kb], 0, 0, 0);
            }
        }

        // in-register softmax (pair l, l^32 holds all 64 k); 2-chain ILP
        float rm0 = accs[0][0], rm1 = accs[1][0];
#pragma unroll
        for (int r = 1; r < 16; r++) {
            rm0 = fmaxf(rm0, accs[0][r]);
            rm1 = fmaxf(rm1, accs[1][r]);
        }
        float rm = fmaxf(rm0, rm1);
        rm = fmaxf(rm, __shfl_xor(rm, 32, 64));
        // defer-max: only rescale when max grew by > 8 (T13)
        if (!__all(rm - m_i <= 8.0f)) {
            float mnew = fmaxf(m_i, rm);
            float alpha = __expf(m_i - mnew);
            m_i = mnew;
            l_i *= alpha;
#pragma unroll
            for (int r = 0; r < 16; r++) { oacc0[r] *= alpha; oacc1[r] *= alpha; }
        }
        float rs0 = 0.f, rs1 = 0.f;
#pragma unroll
        for (int r = 0; r < 16; r++) {
            float p0 = __expf(accs[0][r] - m_i);
            float p1 = __expf(accs[1][r] - m_i);
            accs[0][r] = p0; accs[1][r] = p1;
            rs0 += p0; rs1 += p1;
        }
        float rs = rs0 + rs1;
        rs += __shfl_xor(rs, 32, 64);
        l_i += rs;

        // pack P to bf16 dwords; dwv[kb*8+2a+d] = P[kl=8a+4hi+2d+{0,1}]
        unsigned dwv[16];
#pragma unroll
        for (int kb = 0; kb < 2; kb++)
#pragma unroll
            for (int a = 0; a < 4; a++) {
                dwv[kb * 8 + 2 * a]     = pkbf(accs[kb][4 * a], accs[kb][4 * a + 1]);
                dwv[kb * 8 + 2 * a + 1] = pkbf(accs[kb][4 * a + 2], accs[kb][4 * a + 3]);
            }
        // half-exchange lane<->lane^32 -> pb[c]: P[q=lq][k=c*16+hi*8+j]
        bf16x8 pb[4];
#pragma unroll
        for (int c = 0; c < 4; c++) {
            const int base = (c >> 1) * 8 + (c & 1) * 4;
            unsigned e0 = dwv[base],     e1 = dwv[base + 1];
            unsigned o0 = dwv[base + 2], o1 = dwv[base + 3];
            uintx4 cw;
#if __has_builtin(__builtin_amdgcn_permlane32_swap)
            auto r0 = __builtin_amdgcn_permlane32_swap(e0, o0, false, false);
            auto r1 = __builtin_amdgcn_permlane32_swap(e1, o1, false, false);
            cw[0] = r0[0]; cw[1] = r1[0]; cw[2] = r0[1]; cw[3] = r1[1];
#else
            unsigned s0 = hi ? e0 : o0, s1 = hi ? e1 : o1;
            unsigned k0 = hi ? o0 : e0, k1 = hi ? o1 : e1;
            unsigned x0 = __shfl_xor((int)s0, 32, 64);
            unsigned x1 = __shfl_xor((int)s1, 32, 64);
            cw[0] = hi ? x0 : k0; cw[1] = hi ? x1 : k1;
            cw[2] = hi ? k0 : x0; cw[3] = hi ? k1 : x1;
#endif
            __builtin_memcpy(&pb[c], &cw, 16);
        }

        // PV: O^T[d][q] += V^T[d][k] P[q][k]
#pragma unroll
        for (int c = 0; c < 4; c++) {
            bf16x8 vf0 = *(const bf16x8*)&sKV[cb][1][lq][c * 16 + hi * 8];
            bf16x8 vf1 = *(const bf16x8*)&sKV[cb][1][32 + lq][c * 16 + hi * 8];
            oacc0 = __builtin_amdgcn_mfma_f32_32x32x16_bf16(vf0, pb[c], oacc0, 0, 0, 0);
            oacc1 = __builtin_amdgcn_mfma_f32_32x32x16_bf16(vf1, pb[c], oacc1, 0, 0, 0);
        }
        if (more) STORE_KV(cb ^ 1);            // other buffer; safe post-barrier
    }
#undef LOAD_KV
#undef STORE_KV

    // transpose O^T -> O via LDS bounce (sKV dead after barrier)
    float linv = 1.0f / l_i;
    __syncthreads();
    bf16 (*sO)[72] = reinterpret_cast<bf16(*)[72]>(&sKV[0][0][0][0]);
#pragma unroll
    for (int r = 0; r < 16; r++) {
        int dl = (r & 3) + 8 * (r >> 2) + 4 * hi;
        sO[w * 32 + lq][dl]      = (bf16)(oacc0[r] * linv);
        sO[w * 32 + lq][32 + dl] = (bf16)(oacc1[r] * linv);
    }
    __syncthreads();
    {
        int row = t >> 1, ch = (t & 1) * 32;
        bf16* dst = &O[(size_t)(b * NSEQ + q0 + row) * DMODEL + h * 64 + ch];
#pragma unroll
        for (int k = 0; k < 4; k++)
            *(bf16x8*)(dst + k * 8) = *(const bf16x8*)&sO[row][ch + k * 8];
    }
}

// ---------------------------------------------------------------------------
// residual + LN over two f32 partial-product arrays (main path)
__global__ __launch_bounds__(256) void residual_ln2(const float* __restrict__ X,
        const float* __restrict__ Y0, const float* __restrict__ Y1,
        const float* __restrict__ gamma, const float* __restrict__ beta,
        float* __restrict__ out)
{
    __shared__ float red[8];
    int row = blockIdx.x, t = threadIdx.x;
    size_t base = (size_t)row * DMODEL + t * 4;
    f32x4 xv = *(const f32x4*)&X[base];
    f32x4 y0 = *(const f32x4*)&Y0[base];
    f32x4 y1 = *(const f32x4*)&Y1[base];
    float s[4], sum = 0.f, sq = 0.f;
    for (int i = 0; i < 4; i++) {
        s[i] = xv[i] + y0[i] + y1[i];
        sum += s[i]; sq += s[i] * s[i];
    }
    for (int o = 32; o; o >>= 1) { sum += __shfl_xor(sum, o, 64); sq += __shfl_xor(sq, o, 64); }
    if ((t & 63) == 0) { red[t >> 6] = sum; red[4 + (t >> 6)] = sq; }
    __syncthreads();
    sum = red[0] + red[1] + red[2] + red[3];
    sq  = red[4] + red[5] + red[6] + red[7];
    float mean = sum * (1.0f / DMODEL);
    float var  = sq  * (1.0f / DMODEL) - mean * mean;
    float rstd = rsqrtf(var + 1e-5f);
    f32x4 gv = *(const f32x4*)&gamma[t * 4];
    f32x4 bv = *(const f32x4*)&beta[t * 4];
    f32x4 ov;
    for (int i = 0; i < 4; i++)
        ov[i] = (s[i] - mean) * rstd * gv[i] + bv[i];
    *(f32x4*)&out[base] = ov;
}

// bf16-partial variant (fallback paths)
__global__ __launch_bounds__(256) void residual_ln(const float* __restrict__ X,
        const bf16* __restrict__ Y, const float* __restrict__ gamma,
        const float* __restrict__ beta, float* __restrict__ out)
{
    __shared__ float red[8];
    int row = blockIdx.x, t = threadIdx.x;
    size_t base = (size_t)row * DMODEL + t * 4;
    f32x4  xv = *(const f32x4*)&X[base];
    bf16x4 yv = *(const bf16x4*)&Y[base];
    float s[4], sum = 0.f, sq = 0.f;
    for (int i = 0; i < 4; i++) {
        s[i] = xv[i] + (float)yv[i];
        sum += s[i]; sq += s[i] * s[i];
    }
    for (int o = 32; o; o >>= 1) { sum += __shfl_xor(sum, o, 64); sq += __shfl_xor(sq, o, 64); }
    if ((t & 63) == 0) { red[t >> 6] = sum; red[4 + (t >> 6)] = sq; }
    __syncthreads();
    sum = red[0] + red[1] + red[2] + red[3];
    sq  = red[4] + red[5] + red[6] + red[7];
    float mean = sum * (1.0f / DMODEL);
    float var  = sq  * (1.0f / DMODEL) - mean * mean;
    float rstd = rsqrtf(var + 1e-5f);
    f32x4 gv = *(const f32x4*)&gamma[t * 4];
    f32x4 bv = *(const f32x4*)&beta[t * 4];
    f32x4 ov;
    for (int i = 0; i < 4; i++)
        ov[i] = (s[i] - mean) * rstd * gv[i] + bv[i];
    *(f32x4*)&out[base] = ov;
}

// ---------------------------------------------------------------------------
extern "C" void kernel_launch(void* const* d_in, const int* in_sizes, int n_in,
                              void* d_out, int out_size, void* d_ws, size_t ws_size,
                              hipStream_t stream)
{
    const float* queries = (const float*)d_in[0];
    const float* keys    = (const float*)d_in[1];
    const float* values  = (const float*)d_in[2];
    const int*   amask   = (const int*)d_in[3];
    const float* Wq = (const float*)d_in[4];  const float* bq = (const float*)d_in[5];
    const float* Wk = (const float*)d_in[6];  const float* bk = (const float*)d_in[7];
    const float* Wv = (const float*)d_in[8];  const float* bv = (const float*)d_in[9];
    const float* Wo = (const float*)d_in[10]; const float* bo = (const float*)d_in[11];
    const float* mk = (const float*)d_in[12]; const float* mv = (const float*)d_in[13];
    const float* gamma = (const float*)d_in[14]; const float* beta = (const float*)d_in[15];
    float* out = (float*)d_out;

    bf16* Qb = (bf16*)(out + (size_t)2 * 1024 * 1024);   // d_out upper 8 MB
    const size_t SB  = (size_t)NSEQ * DMODEL;            // 1,048,576 elems
    const size_t KVB = (size_t)NKV * DMODEL;             // 1,114,112 elems
    dim3 gb(256);

    // main path needs Kb + Vt + Ab(q,k,v bf16) + Wb(4 matrices bf16):
    const size_t need_r10 = (2 * 4 * KVB + 3 * 4 * SB + 4 * SB) * sizeof(bf16);

    if (ws_size >= need_r10) {
        // ---------- bf16 + global_load_lds path (ws >= ~49 MB) ----------
        bf16* Kb = (bf16*)d_ws;            // [4][1088][1024]
        bf16* Vt = Kb + 4 * KVB;           // [4*16*64][1088]
        bf16* Ab = Vt + 4 * KVB;           // [3][4][1024][1024] bf16 (q,k,v)
        bf16* Wb = Ab + 12 * SB;           // [4][1024][1024] bf16 (Wq,Wk,Wv,Wo)
        // f32 partial-product buffers for the K-split O-proj (dead regions):
        float* PR0 = (float*)Ab;           // 16 MB in dead Ab (24 MB)
        float* PR1 = (float*)d_ws;         // 16 MB in dead Kb+Vt (17.8 MB)

        CvtArgs ca;
        ca.s[0] = queries; ca.s[1] = keys; ca.s[2] = values;
        ca.s[3] = Wq; ca.s[4] = Wk; ca.s[5] = Wv; ca.s[6] = Wo;
        ca.mk = mk; ca.mv = mv;
        prep<<<dim3(8192 + 1024), gb, 0, stream>>>(ca, Ab, Kb, Vt);

        GemmArgsB gq{Ab,          Wb,          bq, Qb, (int)SB,  0, 0};
        GemmArgsB gk{Ab + 4 * SB, Wb + SB,     bk, Kb, (int)KVB, 0, 0};
        GemmArgsB gv{Ab + 8 * SB, Wb + 2 * SB, bv, Vt, 0,        1, 0};
        gemm128_lds<DMODEL><<<dim3(8, 32, 3), gb, 0, stream>>>(gq, gk, gv);

        attn_flash<<<dim3(8, 64), gb, 0, stream>>>(Qb, Kb, Vt, amask, Qb);

        // O-proj, 2-way K-split (z = slice), f32 partials; bias in slice 0
        GemmArgsB go0{Qb, Wb + 3 * SB, bo,      PR0, 0, 2, 0};
        GemmArgsB go1{Qb, Wb + 3 * SB, nullptr, PR1, 0, 2, 512};
        gemm128_lds<512><<<dim3(8, 32, 2), gb, 0, stream>>>(go0, go1, go1);

        residual_ln2<<<dim3(4096), gb, 0, stream>>>(queries, PR0, PR1,
                                                    gamma, beta, out);
    } else if (ws_size >= (size_t)2 * 4 * KVB * sizeof(bf16)) {
        // ---------- batched f32-staged fallback (ws >= 17,825,792 B) ----------
        bf16* Kb = (bf16*)d_ws;            // [4][1088][1024]
        bf16* Vt = Kb + 4 * KVB;           // [4*16*64][1088]
        bf16* PR = Kb;                     // [4096][1024] aliases dead Kb

        GemmArgs gq{queries, Wq, bq, Qb, (int)SB,  0};
        GemmArgs gk{keys,    Wk, bk, Kb, (int)KVB, 0};
        GemmArgs gv{values,  Wv, bv, Vt, 0,        1};
        gemm128<false><<<dim3(8, 32, 3), gb, 0, stream>>>(gq, gk, gv);
        fill_mem<<<dim3(1024), gb, 0, stream>>>(mk, mv, Kb, Vt);
        attn_flash<<<dim3(8, 64), gb, 0, stream>>>(Qb, Kb, Vt, amask, Qb);
        GemmArgs go{Qb, Wo, bo, PR, (int)SB, 0};
        gemm128<true><<<dim3(8, 32, 1), gb, 0, stream>>>(go, go, go);
        residual_ln<<<dim3(4096), gb, 0, stream>>>(queries, PR, gamma, beta, out);
    } else {
        // ---------- per-batch fallback (ws >= 4,456,448 B) ----------
        bf16* Kb = (bf16*)d_ws;            // [1088][1024]
        bf16* Vt = Kb + KVB;               // [16*64][1088]
        bf16* PR = Kb;

        GemmArgs gq{queries, Wq, bq, Qb, (int)SB, 0};
        gemm128<false><<<dim3(8, 32, 1), gb, 0, stream>>>(gq, gq, gq);
        for (int b = 0; b < 4; b++) {
            GemmArgs gk{keys   + b * SB, Wk, bk, Kb, 0, 0};
            GemmArgs gv{values + b * SB, Wv, bv, Vt, 0, 1};
            gemm128<false><<<dim3(8, 8, 2), gb, 0, stream>>>(gk, gv, gv);
            fill_mem<<<dim3(256), gb, 0, stream>>>(mk, mv, Kb, Vt);
            attn_flash<<<dim3(8, 16), gb, 0, stream>>>(Qb + b * SB, Kb, Vt,
                                                       amask + b * NSEQ, Qb + b * SB);
            GemmArgs go{Qb + b * SB, Wo, bo, PR, 0, 0};
            gemm128<true><<<dim3(8, 8, 1), gb, 0, stream>>>(go, go, go);
            residual_ln<<<dim3(1024), gb, 0, stream>>>(queries + b * SB, PR,
                                                       gamma, beta, out + b * SB);
        }
    }
}